// Round 11
// baseline (605.978 us; speedup 1.0000x reference)
//
#include <hip/hip_runtime.h>

// PropLayer: 3 weighted segment-sums + passthrough.
// Bucketed-CSR (fixed caps, one atomic pass) + copy co-scheduled with fill.
// Meta stores are NON-TEMPORAL (no write-allocate line-fill reads); copy
// reads are non-temporal (no L2/L3 pollution). Gather: one wave per venue
// row (pi then hp, plain nt store, no atomics); Poisson-tail overflow edges
// handled by a post-pass scatter.
// out layout (floats): [paper N_P*256][author N_A*256][venue N_V*256]
// counter layout:      [author 0..N_A) | pi N_A..+N_V) | hp ..+N_V)

typedef float f32x4 __attribute__((ext_vector_type(4)));
typedef int   i32x2 __attribute__((ext_vector_type(2)));

constexpr int ACAP  = 16;   // author bucket capacity (mean deg 6.7)
constexpr int PCAP  = 48;   // pi-venue bucket capacity (mean 30)
constexpr int HCAP  = 144;  // hp-venue bucket capacity (mean 100)
constexpr int CPW   = 4;    // copy rows per wave

// ---------------- copy helper (nt load + nt store) ----------------

__device__ __forceinline__ void copy_rows(const float* __restrict__ paper_h,
                                          float* __restrict__ out_paper,
                                          int j, int lane, int n_paper)
{
    int r0 = j * CPW;
    if (r0 >= n_paper) return;
    int r1 = min(r0 + CPW, n_paper);
    f32x4 v[CPW];
    #pragma unroll
    for (int i = 0; i < CPW; ++i)
        if (r0 + i < r1)
            v[i] = __builtin_nontemporal_load(
                reinterpret_cast<const f32x4*>(paper_h + (size_t)(r0 + i) * 256) + lane);
    #pragma unroll
    for (int i = 0; i < CPW; ++i)
        if (r0 + i < r1)
            __builtin_nontemporal_store(v[i],
                reinterpret_cast<f32x4*>(out_paper + (size_t)(r0 + i) * 256) + lane);
}

// ---------------- K1: bucket fill (nt meta stores) + full copy ----------------

__global__ __launch_bounds__(256) void fill_copy_kernel(
    const int* __restrict__ wb_dst, const int* __restrict__ wb_src,
    const float* __restrict__ wb_w, int E_wb,
    const int* __restrict__ pi_dst, const int* __restrict__ pi_src,
    const float* __restrict__ pi_alpha, const float* __restrict__ pi_w, int E_pi,
    const int* __restrict__ hp_dst, const int* __restrict__ hp_src,
    const float* __restrict__ hp_feat, const float* __restrict__ hp_alpha, int E_hp,
    int n_author, int n_venue,
    int* __restrict__ cnts,               // [ncat]: author | pi | hp
    i32x2* __restrict__ ameta, i32x2* __restrict__ pmeta, i32x2* __restrict__ hmeta,
    int* __restrict__ ovf_cnt, int4* __restrict__ ovf,
    const float* __restrict__ paper_h, float* __restrict__ out_paper,
    int n_paper, int copy_blocks)
{
    if ((int)blockIdx.x < copy_blocks) {
        int j = (int)((blockIdx.x * 256 + threadIdx.x) >> 6);
        copy_rows(paper_h, out_paper, j, threadIdx.x & 63, n_paper);
        return;
    }
    int e = (blockIdx.x - copy_blocks) * 256 + threadIdx.x;
    int gidx, row, src, cap; float w; i32x2* meta;
    if (e < E_wb) {
        row = wb_dst[e]; gidx = row; src = wb_src[e]; w = wb_w[e];
        meta = ameta; cap = ACAP;
    } else if (e < E_wb + E_pi) {
        int i = e - E_wb;
        row = pi_dst[i]; gidx = n_author + row; src = pi_src[i];
        w = pi_alpha[i] * pi_w[i];
        meta = pmeta; cap = PCAP;
    } else if (e < E_wb + E_pi + E_hp) {
        int i = e - E_wb - E_pi;
        row = hp_dst[i]; gidx = n_author + n_venue + row; src = hp_src[i];
        w = hp_feat[i] * hp_alpha[i];
        meta = hmeta; cap = HCAP;
    } else return;

    int pos = atomicAdd(&cnts[gidx], 1);
    if (pos < cap) {
        i32x2 m; m.x = src; m.y = __float_as_int(w);
        __builtin_nontemporal_store(m, &meta[(size_t)row * cap + pos]);
    } else {
        int op = atomicAdd(ovf_cnt, 1);
        ovf[op] = make_int4(src, gidx, __float_as_int(w), 0);
    }
}

// ---------------- K2: gather (venue waves first, then author) ----------------

__device__ __forceinline__ void gather_rows(const float* __restrict__ h,
    const i32x2* __restrict__ meta, int beg, int end, int lane, f32x4& acc)
{
    for (int p = beg; p < end; p += 8) {
        int s[8]; float w[8];
        #pragma unroll
        for (int i = 0; i < 8; ++i) {
            int q = p + i;
            bool ok = q < end;
            i32x2 m = meta[ok ? q : beg];
            s[i] = m.x;
            w[i] = ok ? __int_as_float(m.y) : 0.f;
        }
        f32x4 v[8];
        #pragma unroll
        for (int i = 0; i < 8; ++i)
            v[i] = *(reinterpret_cast<const f32x4*>(h + (size_t)s[i] * 256) + lane);
        #pragma unroll
        for (int i = 0; i < 8; ++i)
            acc += v[i] * w[i];
    }
}

__global__ __launch_bounds__(256) void gather_kernel(
    const float* __restrict__ paper_h, const float* __restrict__ author_h,
    const int* __restrict__ cnts,
    const i32x2* __restrict__ ameta, const i32x2* __restrict__ pmeta,
    const i32x2* __restrict__ hmeta,
    float* __restrict__ out_author, float* __restrict__ out_venue,
    int n_author, int n_venue)
{
    int wid  = (int)((blockIdx.x * blockDim.x + threadIdx.x) >> 6);
    int lane = threadIdx.x & 63;

    if (wid < n_venue) {
        // one wave per venue row: pi (paper_h) then hp (author_h), single store
        int row = wid;
        f32x4 acc = {0.f, 0.f, 0.f, 0.f};
        {
            int cnt = min(cnts[n_author + row], PCAP);
            gather_rows(paper_h, pmeta + (size_t)row * PCAP, 0, cnt, lane, acc);
        }
        {
            int cnt = min(cnts[n_author + n_venue + row], HCAP);
            gather_rows(author_h, hmeta + (size_t)row * HCAP, 0, cnt, lane, acc);
        }
        __builtin_nontemporal_store(acc,
            reinterpret_cast<f32x4*>(out_venue + (size_t)row * 256) + lane);
    } else if (wid < n_venue + n_author) {
        int row = wid - n_venue;
        f32x4 acc = {0.f, 0.f, 0.f, 0.f};
        int cnt = min(cnts[row], ACAP);
        gather_rows(paper_h, ameta + (size_t)row * ACAP, 0, cnt, lane, acc);
        __builtin_nontemporal_store(acc,
            reinterpret_cast<f32x4*>(out_author + (size_t)row * 256) + lane);
    }
}

// ---------------- K3: overflow scatter (Poisson tail, ~hundreds of edges) ----------------

__global__ __launch_bounds__(256) void ovf_scatter_kernel(
    const int* __restrict__ ovf_cnt, const int4* __restrict__ ovf,
    const float* __restrict__ paper_h, const float* __restrict__ author_h,
    float* __restrict__ out_author, float* __restrict__ out_venue,
    int n_author, int n_venue)
{
    int n = *ovf_cnt;
    if (n <= 0) return;
    int nw   = (int)((gridDim.x * blockDim.x) >> 6);
    int wid  = (int)((blockIdx.x * blockDim.x + threadIdx.x) >> 6);
    int lane = threadIdx.x & 63;
    for (int i = wid; i < n; i += nw) {
        int4 t = ovf[i];
        const float* h; float* dst;
        if (t.y < n_author)                { h = paper_h;  dst = out_author + (size_t)t.y * 256; }
        else if (t.y < n_author + n_venue) { h = paper_h;  dst = out_venue + (size_t)(t.y - n_author) * 256; }
        else                               { h = author_h; dst = out_venue + (size_t)(t.y - n_author - n_venue) * 256; }
        float w = __int_as_float(t.z);
        f32x4 v = *(reinterpret_cast<const f32x4*>(h + (size_t)t.x * 256) + lane);
        float* d = dst + (size_t)lane * 4;
        unsafeAtomicAdd(d + 0, v.x * w);
        unsafeAtomicAdd(d + 1, v.y * w);
        unsafeAtomicAdd(d + 2, v.z * w);
        unsafeAtomicAdd(d + 3, v.w * w);
    }
}

// ---------------- fallback (atomic scatter path) ----------------

__global__ __launch_bounds__(256) void edge_scatter_kernel(
    const float* __restrict__ src_h, const int* __restrict__ src_idx,
    const int* __restrict__ dst_idx, const float* __restrict__ w0,
    const float* __restrict__ w1, float* __restrict__ out, int n_edges)
{
    int tid = blockIdx.x * blockDim.x + threadIdx.x;
    int e = tid >> 6;
    if (e >= n_edges) return;
    int lane = tid & 63;
    float w = w0[e];
    if (w1) w *= w1[e];
    const f32x4 v = *(reinterpret_cast<const f32x4*>(
                        src_h + (size_t)src_idx[e] * 256) + lane);
    float* dst = out + (size_t)dst_idx[e] * 256 + (size_t)lane * 4;
    unsafeAtomicAdd(dst + 0, v.x * w);
    unsafeAtomicAdd(dst + 1, v.y * w);
    unsafeAtomicAdd(dst + 2, v.z * w);
    unsafeAtomicAdd(dst + 3, v.w * w);
}

extern "C" void kernel_launch(void* const* d_in, const int* in_sizes, int n_in,
                              void* d_out, int out_size, void* d_ws, size_t ws_size,
                              hipStream_t stream)
{
    const float* paper_h  = (const float*)d_in[0];
    const float* author_h = (const float*)d_in[1];
    const int*   wb_src   = (const int*)d_in[2];
    const int*   wb_dst   = (const int*)d_in[3];
    const float* wb_w     = (const float*)d_in[4];
    const int*   pi_src   = (const int*)d_in[5];
    const int*   pi_dst   = (const int*)d_in[6];
    const float* pi_alpha = (const float*)d_in[7];
    const float* pi_w     = (const float*)d_in[8];
    const int*   hp_src   = (const int*)d_in[9];
    const int*   hp_dst   = (const int*)d_in[10];
    const float* hp_feat  = (const float*)d_in[11];
    const float* hp_alpha = (const float*)d_in[12];

    const int D = 256;
    const int n_paper  = in_sizes[0] / D;
    const int n_author = in_sizes[1] / D;
    const int E_wb = in_sizes[2];
    const int E_pi = in_sizes[5];
    const int E_hp = in_sizes[9];
    const int n_venue = out_size / D - n_paper - n_author;
    const int E_tot = E_wb + E_pi + E_hp;
    const int ncat  = n_author + 2 * n_venue;

    float* out        = (float*)d_out;
    float* out_paper  = out;
    float* out_author = out + (size_t)n_paper * D;
    float* out_venue  = out_author + (size_t)n_author * D;

    // ---- workspace layout (16B-aligned sections) ----
    auto align16 = [](size_t b) { return (b + 15) & ~(size_t)15; };
    char* base = (char*)d_ws;
    size_t off = 0;
    int*  cnts    = (int*)(base + off);  off += (size_t)ncat * 4;
    int*  ovf_cnt = (int*)(base + off);  off += 4;           // contiguous with cnts: one memset
    size_t zero_bytes = off;
    off = align16(off);
    int4*  ovf    = (int4*)(base + off);  off += (size_t)E_tot * 16;  // worst-case safe
    i32x2* ameta  = (i32x2*)(base + off); off += (size_t)n_author * ACAP * 8;
    i32x2* pmeta  = (i32x2*)(base + off); off += (size_t)n_venue * PCAP * 8;
    i32x2* hmeta  = (i32x2*)(base + off); off += (size_t)n_venue * HCAP * 8;
    size_t need_bytes = off;

    if (ws_size < need_bytes) {
        // fallback: atomic scatter path
        hipMemsetAsync(out_author, 0,
                       ((size_t)n_author + n_venue) * D * sizeof(float), stream);
        hipMemcpyAsync(out_paper, paper_h, (size_t)n_paper * D * sizeof(float),
                       hipMemcpyDeviceToDevice, stream);
        auto launch = [&](const float* sh, const int* si, const int* di,
                          const float* w0, const float* w1, float* dst, int E) {
            if (E <= 0) return;
            edge_scatter_kernel<<<(E + 3) / 4, 256, 0, stream>>>(sh, si, di, w0, w1, dst, E);
        };
        launch(paper_h,  wb_src, wb_dst, wb_w,     nullptr,  out_author, E_wb);
        launch(paper_h,  pi_src, pi_dst, pi_alpha, pi_w,     out_venue,  E_pi);
        launch(author_h, hp_src, hp_dst, hp_feat,  hp_alpha, out_venue,  E_hp);
        return;
    }

    // zero cursors + overflow count only (no output memsets needed)
    hipMemsetAsync(cnts, 0, zero_bytes, stream);

    // K1: full copy (blocks first) + bucket fill
    {
        const int copy_waves  = (n_paper + CPW - 1) / CPW;
        const int copy_blocks = (copy_waves * 64 + 255) / 256;
        const int fill_blocks = (E_tot + 255) / 256;
        fill_copy_kernel<<<copy_blocks + fill_blocks, 256, 0, stream>>>(
            wb_dst, wb_src, wb_w, E_wb,
            pi_dst, pi_src, pi_alpha, pi_w, E_pi,
            hp_dst, hp_src, hp_feat, hp_alpha, E_hp,
            n_author, n_venue, cnts, ameta, pmeta, hmeta, ovf_cnt, ovf,
            paper_h, out_paper, n_paper, copy_blocks);
    }

    // K2: gather (venue waves first, author waves backfill)
    {
        const long long total_waves = (long long)n_venue + n_author;
        const int blocks = (int)((total_waves * 64 + 255) / 256);
        gather_kernel<<<blocks, 256, 0, stream>>>(
            paper_h, author_h, cnts, ameta, pmeta, hmeta,
            out_author, out_venue, n_author, n_venue);
    }

    // K3: overflow tail (Poisson-tail edges only)
    ovf_scatter_kernel<<<64, 256, 0, stream>>>(
        ovf_cnt, ovf, paper_h, author_h, out_author, out_venue, n_author, n_venue);
}

// Round 12
// 583.033 us; speedup vs baseline: 1.0394x; 1.0394x over previous
//
#include <hip/hip_runtime.h>

// PropLayer: 3 weighted segment-sums + passthrough.
// FINAL structure (round-9 configuration, reverting the round-11 nt experiment):
//  - Bucketed-CSR, one atomic pass, fixed caps; meta stays CACHE-RESIDENT
//    (plain stores) because K2's meta reads depend on L2/L3 hits.
//  - Full paper copy co-scheduled with the bucket fill (copy blocks first).
//  - Gather: one wave per venue row (pi then hp), one wave per author row,
//    plain nt output stores, no atomics, no output memsets.
//  - Poisson-tail overflow edges via post-pass atomic scatter.
// out layout (floats): [paper N_P*256][author N_A*256][venue N_V*256]
// counter layout:      [author 0..N_A) | pi N_A..+N_V) | hp ..+N_V)

typedef float f32x4 __attribute__((ext_vector_type(4)));

constexpr int ACAP  = 16;   // author bucket capacity (mean deg 6.7)
constexpr int PCAP  = 48;   // pi-venue bucket capacity (mean 30)
constexpr int HCAP  = 144;  // hp-venue bucket capacity (mean 100)
constexpr int CPW   = 4;    // copy rows per wave

// ---------------- copy helper ----------------

__device__ __forceinline__ void copy_rows(const float* __restrict__ paper_h,
                                          float* __restrict__ out_paper,
                                          int j, int lane, int n_paper)
{
    int r0 = j * CPW;
    if (r0 >= n_paper) return;
    int r1 = min(r0 + CPW, n_paper);
    f32x4 v[CPW];
    #pragma unroll
    for (int i = 0; i < CPW; ++i)
        if (r0 + i < r1)
            v[i] = *(reinterpret_cast<const f32x4*>(paper_h + (size_t)(r0 + i) * 256) + lane);
    #pragma unroll
    for (int i = 0; i < CPW; ++i)
        if (r0 + i < r1)
            __builtin_nontemporal_store(v[i],
                reinterpret_cast<f32x4*>(out_paper + (size_t)(r0 + i) * 256) + lane);
}

// ---------------- K1: bucket fill + full copy ----------------

__global__ __launch_bounds__(256) void fill_copy_kernel(
    const int* __restrict__ wb_dst, const int* __restrict__ wb_src,
    const float* __restrict__ wb_w, int E_wb,
    const int* __restrict__ pi_dst, const int* __restrict__ pi_src,
    const float* __restrict__ pi_alpha, const float* __restrict__ pi_w, int E_pi,
    const int* __restrict__ hp_dst, const int* __restrict__ hp_src,
    const float* __restrict__ hp_feat, const float* __restrict__ hp_alpha, int E_hp,
    int n_author, int n_venue,
    int* __restrict__ cnts,               // [ncat]: author | pi | hp
    int2* __restrict__ ameta, int2* __restrict__ pmeta, int2* __restrict__ hmeta,
    int* __restrict__ ovf_cnt, int4* __restrict__ ovf,
    const float* __restrict__ paper_h, float* __restrict__ out_paper,
    int n_paper, int copy_blocks)
{
    if ((int)blockIdx.x < copy_blocks) {
        int j = (int)((blockIdx.x * 256 + threadIdx.x) >> 6);
        copy_rows(paper_h, out_paper, j, threadIdx.x & 63, n_paper);
        return;
    }
    int e = (blockIdx.x - copy_blocks) * 256 + threadIdx.x;
    int gidx, row, src, cap; float w; int2* meta;
    if (e < E_wb) {
        row = wb_dst[e]; gidx = row; src = wb_src[e]; w = wb_w[e];
        meta = ameta; cap = ACAP;
    } else if (e < E_wb + E_pi) {
        int i = e - E_wb;
        row = pi_dst[i]; gidx = n_author + row; src = pi_src[i];
        w = pi_alpha[i] * pi_w[i];
        meta = pmeta; cap = PCAP;
    } else if (e < E_wb + E_pi + E_hp) {
        int i = e - E_wb - E_pi;
        row = hp_dst[i]; gidx = n_author + n_venue + row; src = hp_src[i];
        w = hp_feat[i] * hp_alpha[i];
        meta = hmeta; cap = HCAP;
    } else return;

    int pos = atomicAdd(&cnts[gidx], 1);
    if (pos < cap) {
        meta[(size_t)row * cap + pos] = make_int2(src, __float_as_int(w));
    } else {
        int op = atomicAdd(ovf_cnt, 1);
        ovf[op] = make_int4(src, gidx, __float_as_int(w), 0);
    }
}

// ---------------- K2: gather (venue waves first, then author) ----------------

__device__ __forceinline__ void gather_rows(const float* __restrict__ h,
    const int2* __restrict__ meta, int beg, int end, int lane, f32x4& acc)
{
    for (int p = beg; p < end; p += 8) {
        int s[8]; float w[8];
        #pragma unroll
        for (int i = 0; i < 8; ++i) {
            int q = p + i;
            bool ok = q < end;
            int2 m = meta[ok ? q : beg];
            s[i] = m.x;
            w[i] = ok ? __int_as_float(m.y) : 0.f;
        }
        f32x4 v[8];
        #pragma unroll
        for (int i = 0; i < 8; ++i)
            v[i] = *(reinterpret_cast<const f32x4*>(h + (size_t)s[i] * 256) + lane);
        #pragma unroll
        for (int i = 0; i < 8; ++i)
            acc += v[i] * w[i];
    }
}

__global__ __launch_bounds__(256) void gather_kernel(
    const float* __restrict__ paper_h, const float* __restrict__ author_h,
    const int* __restrict__ cnts,
    const int2* __restrict__ ameta, const int2* __restrict__ pmeta,
    const int2* __restrict__ hmeta,
    float* __restrict__ out_author, float* __restrict__ out_venue,
    int n_author, int n_venue)
{
    int wid  = (int)((blockIdx.x * blockDim.x + threadIdx.x) >> 6);
    int lane = threadIdx.x & 63;

    if (wid < n_venue) {
        // one wave per venue row: pi (paper_h) then hp (author_h), single store
        int row = wid;
        f32x4 acc = {0.f, 0.f, 0.f, 0.f};
        {
            int cnt = min(cnts[n_author + row], PCAP);
            gather_rows(paper_h, pmeta + (size_t)row * PCAP, 0, cnt, lane, acc);
        }
        {
            int cnt = min(cnts[n_author + n_venue + row], HCAP);
            gather_rows(author_h, hmeta + (size_t)row * HCAP, 0, cnt, lane, acc);
        }
        __builtin_nontemporal_store(acc,
            reinterpret_cast<f32x4*>(out_venue + (size_t)row * 256) + lane);
    } else if (wid < n_venue + n_author) {
        int row = wid - n_venue;
        f32x4 acc = {0.f, 0.f, 0.f, 0.f};
        int cnt = min(cnts[row], ACAP);
        gather_rows(paper_h, ameta + (size_t)row * ACAP, 0, cnt, lane, acc);
        __builtin_nontemporal_store(acc,
            reinterpret_cast<f32x4*>(out_author + (size_t)row * 256) + lane);
    }
}

// ---------------- K3: overflow scatter (Poisson tail, ~hundreds of edges) ----------------

__global__ __launch_bounds__(256) void ovf_scatter_kernel(
    const int* __restrict__ ovf_cnt, const int4* __restrict__ ovf,
    const float* __restrict__ paper_h, const float* __restrict__ author_h,
    float* __restrict__ out_author, float* __restrict__ out_venue,
    int n_author, int n_venue)
{
    int n = *ovf_cnt;
    if (n <= 0) return;
    int nw   = (int)((gridDim.x * blockDim.x) >> 6);
    int wid  = (int)((blockIdx.x * blockDim.x + threadIdx.x) >> 6);
    int lane = threadIdx.x & 63;
    for (int i = wid; i < n; i += nw) {
        int4 t = ovf[i];
        const float* h; float* dst;
        if (t.y < n_author)                { h = paper_h;  dst = out_author + (size_t)t.y * 256; }
        else if (t.y < n_author + n_venue) { h = paper_h;  dst = out_venue + (size_t)(t.y - n_author) * 256; }
        else                               { h = author_h; dst = out_venue + (size_t)(t.y - n_author - n_venue) * 256; }
        float w = __int_as_float(t.z);
        f32x4 v = *(reinterpret_cast<const f32x4*>(h + (size_t)t.x * 256) + lane);
        float* d = dst + (size_t)lane * 4;
        unsafeAtomicAdd(d + 0, v.x * w);
        unsafeAtomicAdd(d + 1, v.y * w);
        unsafeAtomicAdd(d + 2, v.z * w);
        unsafeAtomicAdd(d + 3, v.w * w);
    }
}

// ---------------- fallback (atomic scatter path) ----------------

__global__ __launch_bounds__(256) void edge_scatter_kernel(
    const float* __restrict__ src_h, const int* __restrict__ src_idx,
    const int* __restrict__ dst_idx, const float* __restrict__ w0,
    const float* __restrict__ w1, float* __restrict__ out, int n_edges)
{
    int tid = blockIdx.x * blockDim.x + threadIdx.x;
    int e = tid >> 6;
    if (e >= n_edges) return;
    int lane = tid & 63;
    float w = w0[e];
    if (w1) w *= w1[e];
    const f32x4 v = *(reinterpret_cast<const f32x4*>(
                        src_h + (size_t)src_idx[e] * 256) + lane);
    float* dst = out + (size_t)dst_idx[e] * 256 + (size_t)lane * 4;
    unsafeAtomicAdd(dst + 0, v.x * w);
    unsafeAtomicAdd(dst + 1, v.y * w);
    unsafeAtomicAdd(dst + 2, v.z * w);
    unsafeAtomicAdd(dst + 3, v.w * w);
}

extern "C" void kernel_launch(void* const* d_in, const int* in_sizes, int n_in,
                              void* d_out, int out_size, void* d_ws, size_t ws_size,
                              hipStream_t stream)
{
    const float* paper_h  = (const float*)d_in[0];
    const float* author_h = (const float*)d_in[1];
    const int*   wb_src   = (const int*)d_in[2];
    const int*   wb_dst   = (const int*)d_in[3];
    const float* wb_w     = (const float*)d_in[4];
    const int*   pi_src   = (const int*)d_in[5];
    const int*   pi_dst   = (const int*)d_in[6];
    const float* pi_alpha = (const float*)d_in[7];
    const float* pi_w     = (const float*)d_in[8];
    const int*   hp_src   = (const int*)d_in[9];
    const int*   hp_dst   = (const int*)d_in[10];
    const float* hp_feat  = (const float*)d_in[11];
    const float* hp_alpha = (const float*)d_in[12];

    const int D = 256;
    const int n_paper  = in_sizes[0] / D;
    const int n_author = in_sizes[1] / D;
    const int E_wb = in_sizes[2];
    const int E_pi = in_sizes[5];
    const int E_hp = in_sizes[9];
    const int n_venue = out_size / D - n_paper - n_author;
    const int E_tot = E_wb + E_pi + E_hp;
    const int ncat  = n_author + 2 * n_venue;

    float* out        = (float*)d_out;
    float* out_paper  = out;
    float* out_author = out + (size_t)n_paper * D;
    float* out_venue  = out_author + (size_t)n_author * D;

    // ---- workspace layout (16B-aligned sections) ----
    auto align16 = [](size_t b) { return (b + 15) & ~(size_t)15; };
    char* base = (char*)d_ws;
    size_t off = 0;
    int*  cnts    = (int*)(base + off);  off += (size_t)ncat * 4;
    int*  ovf_cnt = (int*)(base + off);  off += 4;           // contiguous with cnts: one memset
    size_t zero_bytes = off;
    off = align16(off);
    int4* ovf     = (int4*)(base + off); off += (size_t)E_tot * 16;  // worst-case safe
    int2* ameta   = (int2*)(base + off); off += (size_t)n_author * ACAP * 8;
    int2* pmeta   = (int2*)(base + off); off += (size_t)n_venue * PCAP * 8;
    int2* hmeta   = (int2*)(base + off); off += (size_t)n_venue * HCAP * 8;
    size_t need_bytes = off;

    if (ws_size < need_bytes) {
        // fallback: atomic scatter path
        hipMemsetAsync(out_author, 0,
                       ((size_t)n_author + n_venue) * D * sizeof(float), stream);
        hipMemcpyAsync(out_paper, paper_h, (size_t)n_paper * D * sizeof(float),
                       hipMemcpyDeviceToDevice, stream);
        auto launch = [&](const float* sh, const int* si, const int* di,
                          const float* w0, const float* w1, float* dst, int E) {
            if (E <= 0) return;
            edge_scatter_kernel<<<(E + 3) / 4, 256, 0, stream>>>(sh, si, di, w0, w1, dst, E);
        };
        launch(paper_h,  wb_src, wb_dst, wb_w,     nullptr,  out_author, E_wb);
        launch(paper_h,  pi_src, pi_dst, pi_alpha, pi_w,     out_venue,  E_pi);
        launch(author_h, hp_src, hp_dst, hp_feat,  hp_alpha, out_venue,  E_hp);
        return;
    }

    // zero cursors + overflow count only (no output memsets needed)
    hipMemsetAsync(cnts, 0, zero_bytes, stream);

    // K1: full copy (blocks first) + bucket fill
    {
        const int copy_waves  = (n_paper + CPW - 1) / CPW;
        const int copy_blocks = (copy_waves * 64 + 255) / 256;
        const int fill_blocks = (E_tot + 255) / 256;
        fill_copy_kernel<<<copy_blocks + fill_blocks, 256, 0, stream>>>(
            wb_dst, wb_src, wb_w, E_wb,
            pi_dst, pi_src, pi_alpha, pi_w, E_pi,
            hp_dst, hp_src, hp_feat, hp_alpha, E_hp,
            n_author, n_venue, cnts, ameta, pmeta, hmeta, ovf_cnt, ovf,
            paper_h, out_paper, n_paper, copy_blocks);
    }

    // K2: gather (venue waves first, author waves backfill)
    {
        const long long total_waves = (long long)n_venue + n_author;
        const int blocks = (int)((total_waves * 64 + 255) / 256);
        gather_kernel<<<blocks, 256, 0, stream>>>(
            paper_h, author_h, cnts, ameta, pmeta, hmeta,
            out_author, out_venue, n_author, n_venue);
    }

    // K3: overflow tail (Poisson-tail edges only)
    ovf_scatter_kernel<<<64, 256, 0, stream>>>(
        ovf_cnt, ovf, paper_h, author_h, out_author, out_venue, n_author, n_venue);
}